// Round 9
// baseline (272.197 us; speedup 1.0000x reference)
//
#include <hip/hip_runtime.h>
#include <hip/hip_bf16.h>

typedef __attribute__((ext_vector_type(8)))  __bf16 bf16x8;
typedef __attribute__((ext_vector_type(16))) float  f32x16;

#define SDIM 49
#define NDIM 1024
#define CDIM 384
#define DDIM 512
#define DMC  64
#define SCALE (1.0f/(SDIM*NDIM))
#define PSLOT 49152   // A(keys) 256x128B = 32KB + B(q) 128x128B = 16KB; 2 slots = 96KB

__device__ __forceinline__ void gload16(const void* g, void* l) {
    __builtin_amdgcn_global_load_lds((const __attribute__((address_space(1))) void*)g,
                                     (__attribute__((address_space(3))) void*)l, 16, 0, 0);
}

// ---------------------------------------------------------------------------
// pack + passthrough copy fused from registers (validated R8).
// ---------------------------------------------------------------------------
__global__ __launch_bounds__(512) void pack_copy_kernel(
    const float* __restrict__ xloc, const float* __restrict__ mv,
    const float* __restrict__ cv,   __hip_bfloat16* __restrict__ dst,
    float* __restrict__ cpy)
{
    const int j = blockIdx.x;
    const int d = threadIdx.x;
    float vals[SDIM];
    if (d < CDIM) {
        const float* p = xloc + ((size_t)j * CDIM + d) * SDIM;
        #pragma unroll
        for (int s = 0; s < SDIM; ++s) vals[s] = p[s];
        float* dcp = cpy + ((size_t)j * CDIM + d) * SDIM;
        #pragma unroll
        for (int s = 0; s < SDIM; ++s) dcp[s] = vals[s];
    } else if (d < CDIM + DMC) {
        float v = mv[j * DMC + (d - CDIM)];
        #pragma unroll
        for (int s = 0; s < SDIM; ++s) vals[s] = v;
    } else {
        float v = cv[j * DMC + (d - CDIM - DMC)];
        #pragma unroll
        for (int s = 0; s < SDIM; ++s) vals[s] = v;
    }
    #pragma unroll
    for (int s = 0; s < SDIM; ++s)
        dst[((size_t)s * NDIM + j) * DDIM + d] = __float2bfloat16(vals[s]);
}

__global__ void fpack_kernel(const float* __restrict__ f,
                             __hip_bfloat16* __restrict__ dst, int n)
{
    int i = blockIdx.x * blockDim.x + threadIdx.x;
    if (i < n) dst[i] = __float2bfloat16(f[i]);
}

// ---------------------------------------------------------------------------
// PERSISTENT fused GEMM + partial-LSE, ILP-first: 4 waves/block, 1 wave/SIMD,
// full 512-reg budget per wave so all 24 frag reads stay live under the MFMAs.
// grid = 256 blocks of 256; block (xcd=bid&7, j=bid>>3) owns tiles
// l = j + 32k (l < 392), g = xcd*392 + l; tile g: s=g/64, kb=(g%64)>>4, qb=g&15.
// Tile: 256 keys x 128 q (4 waves = 2 wk x 2 wq, wave 128 keys x 64 q), BK=64.
// SWAPPED operands: D[key,q] = mfma32x32x16(A=K_frag, B=Q_frag);
// C/D (R4-validated): col(q)=lane&31, row(key)=(reg&3)+8*(reg>>2)+4*(lane>>5).
// acc[ka=0..3][qc=0..1] f32x16 (128 regs), frags af[4][4] bf[2][4] (96 regs).
// LDS slot: A rows [256][128B] @0, B rows [128][128B] @32768;
// content[row][col] = G[row][kstep*128 + (col ^ ((row&7)<<4))]; staged with
// linear LDS dest + pre-swizzled global source (validated R4-R8).
// Per K-step: vmcnt(0) [loads issued a full step ago]; barrier; stage12(t+1);
// issue all 24 ds_reads; 32 MFMA (compiler counted-lgkm overlaps reads).
// t=7 stages NEXT TILE's step 0 -> epilogue overlaps those loads.
// ---------------------------------------------------------------------------
__global__ __launch_bounds__(256, 1) void loss_kernel(
    const __hip_bfloat16* __restrict__ Fm,   // [N,512]
    const __hip_bfloat16* __restrict__ Km,   // [S,N,512] keys
    const __hip_bfloat16* __restrict__ Qm,   // [S,N,512] queries (pred2)
    float2* __restrict__ part,               // [S*2048][8]
    float* __restrict__ out)
{
    extern __shared__ __attribute__((aligned(16))) char sm[];   // 2*PSLOT

    const int bid = blockIdx.x;
    const int xcd = bid & 7;
    const int jj  = bid >> 3;

    const int tid  = threadIdx.x;
    const int lane = tid & 63;
    const int wv   = tid >> 6;      // 0..3
    const int r31  = lane & 31;
    const int hi   = lane >> 5;
    const int wk   = wv >> 1;       // 0..1 key half (128 keys)
    const int wq   = wv & 1;        // 0..1 q half (64 q)

    // staging: chunk ch = 8 rows; lane l covers row ch*8+(l>>3), 16B slot l&7;
    // pre-swizzled source col (row&7 == l>>3 since chunks are 8-aligned)
    const int srccol = (((lane & 7) ^ (lane >> 3)) << 4);
    const int lrow   = lane >> 3;

    auto APtr = [&](int g) -> const char* {
        const int s = g >> 6, kb = (g >> 4) & 3;
        return (const char*)Km + ((size_t)s * NDIM + (size_t)kb * 256) * 1024;
    };
    auto BPtr = [&](int g) -> const char* {
        const int s = g >> 6, qb = g & 15;
        return (qb < 8)
            ? ((const char*)Fm + (size_t)qb * 128 * 1024)
            : ((const char*)Qm + ((size_t)s * NDIM + (size_t)(qb - 8) * 128) * 1024);
    };
    auto stage12 = [&](const char* A, const char* B, int ko, char* slot) {
        #pragma unroll
        for (int k = 0; k < 8; ++k) {       // A: 32 chunks, wave takes wv+4k
            const int ch = wv + 4 * k;
            gload16(A + (size_t)(ch * 8 + lrow) * 1024 + ko + srccol,
                    slot + ch * 1024 + lane * 16);
        }
        #pragma unroll
        for (int k = 0; k < 4; ++k) {       // B: 16 chunks
            const int ch = wv + 4 * k;
            gload16(B + (size_t)(ch * 8 + lrow) * 1024 + ko + srccol,
                    slot + 32768 + ch * 1024 + lane * 16);
        }
    };

    // compute-side addressing: A row = wk*128 + ka*32 + r31; B row = wq*64 + qc*32 + r31
    const unsigned xo    = (unsigned)((r31 & 7) << 4);
    const unsigned abase = (unsigned)((wk * 128 + r31) * 128);
    const unsigned bbase = 32768u + (unsigned)((wq * 64 + r31) * 128);

    f32x16 acc[4][2];
    bf16x8 af[4][4], bf[2][4];

    // prologue: first tile's step 0 into slot 0
    {
        const int g0 = xcd * 392 + jj;
        stage12(APtr(g0), BPtr(g0), 0, sm);
    }

    for (int l = jj; l < 392; l += 32) {
        const int g = xcd * 392 + l;
        const char* Ag = APtr(g);
        const char* Bg = BPtr(g);
        const bool hasNext = (l + 32) < 392;
        const int gn = hasNext ? (g + 32) : g;
        const char* An = APtr(gn);
        const char* Bn = BPtr(gn);

        #pragma unroll
        for (int ka = 0; ka < 4; ++ka)
            #pragma unroll
            for (int qc = 0; qc < 2; ++qc) acc[ka][qc] = f32x16{};

        #pragma unroll
        for (int t = 0; t < 8; ++t) {
            const char* sb_ = sm + (size_t)(t & 1) * PSLOT;
            char* ns_ = sm + (size_t)((t + 1) & 1) * PSLOT;
            const bool pf = (t < 7) || hasNext;

            // slot-t loads were issued a full K-step ago -> near-free wait
            asm volatile("s_waitcnt vmcnt(0)" ::: "memory");
            __builtin_amdgcn_s_barrier();

            if (pf) {
                if (t < 7) stage12(Ag, Bg, (t + 1) * 128, ns_);
                else       stage12(An, Bn, 0, ns_);
            }

            // issue ALL 24 ds_reads; frags stay live (96 VGPR, 1 wave/SIMD)
            #pragma unroll
            for (int kc = 0; kc < 4; ++kc) {
                const unsigned co = ((unsigned)(kc * 32 + hi * 16)) ^ xo;
                #pragma unroll
                for (int ka = 0; ka < 4; ++ka)
                    af[ka][kc] = *(const bf16x8*)(sb_ + abase + ka * 4096u + co);
                #pragma unroll
                for (int qc = 0; qc < 2; ++qc)
                    bf[qc][kc] = *(const bf16x8*)(sb_ + bbase + qc * 4096u + co);
            }
            __builtin_amdgcn_s_setprio(1);
            #pragma unroll
            for (int kc = 0; kc < 4; ++kc)
                #pragma unroll
                for (int ka = 0; ka < 4; ++ka)
                    #pragma unroll
                    for (int qc = 0; qc < 2; ++qc)
                        acc[ka][qc] = __builtin_amdgcn_mfma_f32_32x32x16_bf16(
                            af[ka][kc], bf[qc][kc], acc[ka][qc], 0, 0, 0);
            __builtin_amdgcn_s_setprio(0);
        }

        // ---- epilogue (overlaps next tile's in-flight step-0 loads)
        const int s  = g >> 6;
        const int kb = (g >> 4) & 3;
        const int qb = g & 15;

        // lane (r31,hi), acc[ka][qc][r]: q = qb*128 + wq*64 + qc*32 + r31,
        // key = kb*256 + wk*128 + ka*32 + (r&3)+8*(r>>2)+4*hi
        #pragma unroll
        for (int qc = 0; qc < 2; ++qc) {
            float m = -3.0e38f;
            #pragma unroll
            for (int ka = 0; ka < 4; ++ka)
                #pragma unroll
                for (int r = 0; r < 16; ++r) m = fmaxf(m, acc[ka][qc][r]);
            float ss = 0.0f;
            #pragma unroll
            for (int ka = 0; ka < 4; ++ka)
                #pragma unroll
                for (int r = 0; r < 16; ++r) ss += __expf(acc[ka][qc][r] - m);
            // merge hi halves (keys interleave across hi, same q)
            {
                float mo = __shfl_xor(m, 32, 64), so = __shfl_xor(ss, 32, 64);
                float nm = fmaxf(m, mo);
                ss = ss * __expf(m - nm) + so * __expf(mo - nm); m = nm;
            }
            if (!hi) {
                const size_t row = (size_t)s * 2048 + (size_t)qb * 128
                                 + wq * 64 + qc * 32 + r31;
                part[row * 8 + kb * 2 + wk] = make_float2(m, ss);
            }
        }

        // ---- diagonal: q_in_set == key; cond (qb&7) == kb*2+wk;
        // ka = wq*2 + qc; key-row match: hi == (r31>>2)&1, reg = (r31&3)|((r31>>3)<<2)
        if ((qb & 7) == kb * 2 + wk) {
            const int regd = (r31 & 3) | ((r31 >> 3) << 2);
            float d = 0.0f;
            if (hi == ((r31 >> 2) & 1)) {
                if (wq) {
                    #pragma unroll
                    for (int qc = 0; qc < 2; ++qc)
                        #pragma unroll
                        for (int r = 0; r < 16; ++r)
                            if (r == regd) d += acc[2 + qc][qc][r];
                } else {
                    #pragma unroll
                    for (int qc = 0; qc < 2; ++qc)
                        #pragma unroll
                        for (int r = 0; r < 16; ++r)
                            if (r == regd) d += acc[qc][qc][r];
                }
            }
            #pragma unroll
            for (int off = 1; off < 64; off <<= 1) d += __shfl_xor(d, off, 64);
            if (lane == 0) atomicAdd(out, -d * SCALE);
        }
    }
}

// merge the 8 per-(kb,wk) partials of each row -> lse, accumulate loss
__global__ __launch_bounds__(256) void reduce_kernel(
    const float2* __restrict__ part, float* __restrict__ out)
{
    const int row = blockIdx.x * 256 + threadIdx.x;   // 392*256 = 100352 rows
    const float2* p = part + (size_t)row * 8;
    float m = -3.0e38f;
    float2 q[8];
    #pragma unroll
    for (int i = 0; i < 8; ++i) { q[i] = p[i]; m = fmaxf(m, q[i].x); }
    float ssum = 0.0f;
    #pragma unroll
    for (int i = 0; i < 8; ++i) ssum += q[i].y * __expf(q[i].x - m);
    float v = m + __logf(ssum);
    #pragma unroll
    for (int off = 1; off < 64; off <<= 1) v += __shfl_xor(v, off, 64);
    __shared__ float red[4];
    const int lane = threadIdx.x & 63, w = threadIdx.x >> 6;
    if (lane == 0) red[w] = v;
    __syncthreads();
    if (threadIdx.x == 0)
        atomicAdd(out, (red[0] + red[1] + red[2] + red[3]) * SCALE);
}

extern "C" void kernel_launch(void* const* d_in, const int* in_sizes, int n_in,
                              void* d_out, int out_size, void* d_ws, size_t ws_size,
                              hipStream_t stream)
{
    (void)in_sizes; (void)n_in; (void)out_size; (void)ws_size;
    const float* f  = (const float*)d_in[0];
    const float* x  = (const float*)d_in[1];
    const float* xp = (const float*)d_in[2];
    const float* mt = (const float*)d_in[3];
    const float* mp = (const float*)d_in[4];
    const float* ct = (const float*)d_in[5];
    const float* cp = (const float*)d_in[6];
    float* out = (float*)d_out;

    char* ws = (char*)d_ws;
    const size_t packBytes = (size_t)SDIM * NDIM * DDIM * 2;   // 51.4 MB
    __hip_bfloat16* Km = (__hip_bfloat16*)ws;
    __hip_bfloat16* Qm = (__hip_bfloat16*)(ws + packBytes);
    __hip_bfloat16* Fm = (__hip_bfloat16*)(ws + 2 * packBytes);
    float2* part = (float2*)(ws + 2 * packBytes + (size_t)NDIM * DDIM * 2);

    hipMemsetAsync(out, 0, sizeof(float), stream);

    const int sz = NDIM * CDIM * SDIM;
    pack_copy_kernel<<<NDIM, 512, 0, stream>>>(xp, mp, cp, Km, out + 1);
    pack_copy_kernel<<<NDIM, 512, 0, stream>>>(x,  mt, ct, Qm, out + 1 + sz);
    fpack_kernel<<<(NDIM * DDIM + 255) / 256, 256, 0, stream>>>(f, Fm, NDIM * DDIM);

    loss_kernel<<<256, 256, 2 * PSLOT, stream>>>(Fm, Km, Qm, part, out);
    reduce_kernel<<<392, 256, 0, stream>>>(part, out);
}

// Round 10
// 241.716 us; speedup vs baseline: 1.1261x; 1.1261x over previous
//
#include <hip/hip_runtime.h>
#include <hip/hip_bf16.h>

typedef __attribute__((ext_vector_type(8))) __bf16 bf16x8;
typedef __attribute__((ext_vector_type(4))) float  f32x4;

#define SDIM 49
#define NDIM 1024
#define CDIM 384
#define DDIM 512
#define DMC  64
#define SCALE (1.0f/(SDIM*NDIM))
#define SLOT 65536   // A(keys) 32KB + B(q) 32KB per K-step slot; 2 slots = 128KB

__device__ __forceinline__ void gload16(const void* g, void* l) {
    __builtin_amdgcn_global_load_lds((const __attribute__((address_space(1))) void*)g,
                                     (__attribute__((address_space(3))) void*)l, 16, 0, 0);
}

// ---------------------------------------------------------------------------
// pack + passthrough copy fused from registers (validated R8).
// ---------------------------------------------------------------------------
__global__ __launch_bounds__(512) void pack_copy_kernel(
    const float* __restrict__ xloc, const float* __restrict__ mv,
    const float* __restrict__ cv,   __hip_bfloat16* __restrict__ dst,
    float* __restrict__ cpy)
{
    const int j = blockIdx.x;
    const int d = threadIdx.x;
    float vals[SDIM];
    if (d < CDIM) {
        const float* p = xloc + ((size_t)j * CDIM + d) * SDIM;
        #pragma unroll
        for (int s = 0; s < SDIM; ++s) vals[s] = p[s];
        float* dcp = cpy + ((size_t)j * CDIM + d) * SDIM;
        #pragma unroll
        for (int s = 0; s < SDIM; ++s) dcp[s] = vals[s];
    } else if (d < CDIM + DMC) {
        float v = mv[j * DMC + (d - CDIM)];
        #pragma unroll
        for (int s = 0; s < SDIM; ++s) vals[s] = v;
    } else {
        float v = cv[j * DMC + (d - CDIM - DMC)];
        #pragma unroll
        for (int s = 0; s < SDIM; ++s) vals[s] = v;
    }
    #pragma unroll
    for (int s = 0; s < SDIM; ++s)
        dst[((size_t)s * NDIM + j) * DDIM + d] = __float2bfloat16(vals[s]);
}

__global__ void fpack_kernel(const float* __restrict__ f,
                             __hip_bfloat16* __restrict__ dst, int n)
{
    int i = blockIdx.x * blockDim.x + threadIdx.x;
    if (i < n) dst[i] = __float2bfloat16(f[i]);
}

// ---------------------------------------------------------------------------
// PERSISTENT fused GEMM + partial-LSE, MINIMAL-SYNC schedule (m97-style).
// grid = 256 blocks of 512 (8 waves = 2 wk x 4 wq); block (xcd=bid&7, jj)
// owns tiles g = 196*xcd + jj + 32k.  Tile g: s=g>>5, kb=(g>>3)&3, qb=g&7.
// Tile: 256 keys x 256 q, BK=64 (8 K-steps); wave tile 128 keys x 64 q.
// MFMA 16x16x32 bf16: acc[a=0..7][b=0..3] f32x4; C/D col=lane&15,
// row=(lane>>4)*4+reg (validated R6-R8).
// LDS slot: A rows [256][128B] @0, B rows [256][128B] @32K;
// content[row][col] = G[row][kstep*128 + (col ^ ((row&7)<<4))]; linear LDS
// dest + pre-swizzled global source (R4-R8: 0 bank conflicts).
// K-step = ONE __syncthreads (its vmcnt0+lgkm0 drain IS the slot handoff),
// stage8(t+1) pinned first (sched_barrier), then reads+MFMAs compiler-
// scheduled with counted lgkm.  No other barriers, no mid-step drains.
// t=7 stages NEXT TILE's step 0 -> epilogue adds ~1000cy of load slack.
// ---------------------------------------------------------------------------
__global__ __launch_bounds__(512, 2) void loss_kernel(
    const __hip_bfloat16* __restrict__ Fm,   // [N,512]
    const __hip_bfloat16* __restrict__ Km,   // [S,N,512] keys
    const __hip_bfloat16* __restrict__ Qm,   // [S,N,512] queries (pred2)
    float2* __restrict__ part,               // [S*2048][8]
    float* __restrict__ out)
{
    extern __shared__ __attribute__((aligned(16))) char sm[];   // 2*SLOT

    const int bid = blockIdx.x;
    const int xcd = bid & 7;
    const int jj  = bid >> 3;
    const int g0  = 196 * xcd;
    const int gend = g0 + 196;

    const int tid  = threadIdx.x;
    const int lane = tid & 63;
    const int w    = tid >> 6;
    const int l15  = lane & 15;
    const int l4   = lane >> 4;   // 0..3
    const int wk   = w >> 2;      // 0..1 key half
    const int wq   = w & 3;       // 0..3 q quarter

    // staging: thread covers rows c*64 + (tid>>3), 16B col (tid&7)*16;
    // pre-swizzled source col = col ^ ((row&7)<<4)
    const int trow = tid >> 3;
    const int scol = (((tid & 7) ^ ((tid >> 3) & 7)) << 4);

    // compute-side addressing
    const unsigned xo   = (unsigned)((l15 & 7) << 4);
    const unsigned arow = (unsigned)((wk * 128 + l15) * 128);
    const unsigned brow = 32768u + (unsigned)((wq * 64 + l15) * 128);

    auto APtr = [&](int g) -> const char* {
        const int s = g >> 5, kb = (g >> 3) & 3;
        return (const char*)Km + ((size_t)s * NDIM + (size_t)kb * 256) * 1024;
    };
    auto BPtr = [&](int g) -> const char* {
        const int s = g >> 5, qb = g & 7;
        return (qb < 4)
            ? ((const char*)Fm + (size_t)qb * 256 * 1024)
            : ((const char*)Qm + ((size_t)s * NDIM + (size_t)(qb - 4) * 256) * 1024);
    };
    auto stage8 = [&](const char* A, const char* B, int ko, char* slot) {
        #pragma unroll
        for (int c = 0; c < 4; ++c) {
            gload16(A + (size_t)(c * 64 + trow) * 1024 + ko + scol,
                    slot + c * 8192 + tid * 16);
            gload16(B + (size_t)(c * 64 + trow) * 1024 + ko + scol,
                    slot + 32768 + c * 8192 + tid * 16);
        }
    };

    f32x4 acc[8][4];
    bf16x8 afr[8], bfr[4];

    #define READ12(KC) do {                                                   \
        const unsigned co = ((unsigned)((KC) * 64 + l4 * 16)) ^ xo;           \
        _Pragma("unroll")                                                     \
        for (int a = 0; a < 8; ++a)                                           \
            afr[a] = *(const bf16x8*)(sb_ + arow + a * 2048u + co);           \
        _Pragma("unroll")                                                     \
        for (int b = 0; b < 4; ++b)                                           \
            bfr[b] = *(const bf16x8*)(sb_ + brow + b * 2048u + co);           \
    } while (0)

    #define MFMA32() do {                                                     \
        _Pragma("unroll")                                                     \
        for (int a = 0; a < 8; ++a)                                           \
            _Pragma("unroll")                                                 \
            for (int b = 0; b < 4; ++b)                                       \
                acc[a][b] = __builtin_amdgcn_mfma_f32_16x16x32_bf16(          \
                    afr[a], bfr[b], acc[a][b], 0, 0, 0);                      \
    } while (0)

    // prologue: first tile's step 0 into slot 0
    stage8(APtr(g0 + jj), BPtr(g0 + jj), 0, sm);

    for (int g = g0 + jj; g < gend; g += 32) {
        const char* Ag = APtr(g);
        const char* Bg = BPtr(g);
        const bool hasNext = (g + 32) < gend;
        const char* An = hasNext ? APtr(g + 32) : Ag;
        const char* Bn = hasNext ? BPtr(g + 32) : Bg;

        #pragma unroll
        for (int a = 0; a < 8; ++a)
            #pragma unroll
            for (int b = 0; b < 4; ++b) acc[a][b] = f32x4{0.f, 0.f, 0.f, 0.f};

        #pragma unroll
        for (int t = 0; t < 8; ++t) {
            const char* sb_ = sm + (size_t)(t & 1) * SLOT;
            char* ns_ = sm + (size_t)((t + 1) & 1) * SLOT;

            // ONE sync per K-step: drains own gloads (vmcnt0) + barrier =
            // slot t fully written by all waves, prior reads of ns_ done.
            __syncthreads();

            if ((t < 7) || hasNext) {
                const char* sA = (t < 7) ? Ag : An;
                const char* sB = (t < 7) ? Bg : Bn;
                stage8(sA, sB, (t < 7) ? (t + 1) * 128 : 0, ns_);
            }
            __builtin_amdgcn_sched_barrier(0);   // pin stage-issue first

            READ12(0);
            __builtin_amdgcn_s_setprio(1); MFMA32(); __builtin_amdgcn_s_setprio(0);
            READ12(1);
            __builtin_amdgcn_s_setprio(1); MFMA32(); __builtin_amdgcn_s_setprio(0);
        }

        // ---- epilogue (overlaps next tile's in-flight step-0 loads)
        const int s  = g >> 5;
        const int kb = (g >> 3) & 3;
        const int qb = g & 7;

        float q_m[4], q_s[4];
        #pragma unroll
        for (int b = 0; b < 4; ++b) {
            float m = -3.0e38f;
            #pragma unroll
            for (int a = 0; a < 8; ++a)
                #pragma unroll
                for (int r = 0; r < 4; ++r) m = fmaxf(m, acc[a][b][r]);
            float ss = 0.0f;
            #pragma unroll
            for (int a = 0; a < 8; ++a)
                #pragma unroll
                for (int r = 0; r < 4; ++r) ss += __expf(acc[a][b][r] - m);
            #pragma unroll
            for (int off = 16; off <= 32; off <<= 1) {
                float mo = __shfl_xor(m, off, 64);
                float so = __shfl_xor(ss, off, 64);
                float nm = fmaxf(m, mo);
                ss = ss * __expf(m - nm) + so * __expf(mo - nm);
                m = nm;
            }
            q_m[b] = m; q_s[b] = ss;
        }
        if (lane < 16) {
            const size_t rowb = (size_t)s * 2048 + (size_t)qb * 256 + wq * 64 + lane;
            #pragma unroll
            for (int b = 0; b < 4; ++b)
                part[(rowb + b * 16) * 8 + kb * 2 + wk] = make_float2(q_m[b], q_s[b]);
        }

        // diag: block cond kb == qb&3, wave cond wq>>1 == wk; a = (wq&1)*4+b;
        // lane cond l15>>2 == l4, reg r = lane&3 (compile-time indexed).
        if (kb == (qb & 3) && (wq >> 1) == wk) {
            float d = 0.0f;
            const bool lok = (((lane >> 2) & 3) == l4);
            if (wq & 1) {
                #pragma unroll
                for (int b = 0; b < 4; ++b)
                    #pragma unroll
                    for (int r = 0; r < 4; ++r)
                        if (lok && r == (lane & 3)) d += acc[4 + b][b][r];
            } else {
                #pragma unroll
                for (int b = 0; b < 4; ++b)
                    #pragma unroll
                    for (int r = 0; r < 4; ++r)
                        if (lok && r == (lane & 3)) d += acc[b][b][r];
            }
            #pragma unroll
            for (int off = 1; off < 64; off <<= 1) d += __shfl_xor(d, off, 64);
            if (lane == 0) atomicAdd(out, -d * SCALE);
        }
    }
    #undef READ12
    #undef MFMA32
}

// merge the 8 per-(kb,wk) partials of each row -> lse, accumulate loss
__global__ __launch_bounds__(256) void reduce_kernel(
    const float2* __restrict__ part, float* __restrict__ out)
{
    const int row = blockIdx.x * 256 + threadIdx.x;   // 392*256 = 100352 rows
    const float2* p = part + (size_t)row * 8;
    float m = -3.0e38f;
    float2 q[8];
    #pragma unroll
    for (int i = 0; i < 8; ++i) { q[i] = p[i]; m = fmaxf(m, q[i].x); }
    float ssum = 0.0f;
    #pragma unroll
    for (int i = 0; i < 8; ++i) ssum += q[i].y * __expf(q[i].x - m);
    float v = m + __logf(ssum);
    #pragma unroll
    for (int off = 1; off < 64; off <<= 1) v += __shfl_xor(v, off, 64);
    __shared__ float red[4];
    const int lane = threadIdx.x & 63, w = threadIdx.x >> 6;
    if (lane == 0) red[w] = v;
    __syncthreads();
    if (threadIdx.x == 0)
        atomicAdd(out, (red[0] + red[1] + red[2] + red[3]) * SCALE);
}

extern "C" void kernel_launch(void* const* d_in, const int* in_sizes, int n_in,
                              void* d_out, int out_size, void* d_ws, size_t ws_size,
                              hipStream_t stream)
{
    (void)in_sizes; (void)n_in; (void)out_size; (void)ws_size;
    const float* f  = (const float*)d_in[0];
    const float* x  = (const float*)d_in[1];
    const float* xp = (const float*)d_in[2];
    const float* mt = (const float*)d_in[3];
    const float* mp = (const float*)d_in[4];
    const float* ct = (const float*)d_in[5];
    const float* cp = (const float*)d_in[6];
    float* out = (float*)d_out;

    char* ws = (char*)d_ws;
    const size_t packBytes = (size_t)SDIM * NDIM * DDIM * 2;   // 51.4 MB
    __hip_bfloat16* Km = (__hip_bfloat16*)ws;
    __hip_bfloat16* Qm = (__hip_bfloat16*)(ws + packBytes);
    __hip_bfloat16* Fm = (__hip_bfloat16*)(ws + 2 * packBytes);
    float2* part = (float2*)(ws + 2 * packBytes + (size_t)NDIM * DDIM * 2);

    hipMemsetAsync(out, 0, sizeof(float), stream);

    const int sz = NDIM * CDIM * SDIM;
    pack_copy_kernel<<<NDIM, 512, 0, stream>>>(xp, mp, cp, Km, out + 1);
    pack_copy_kernel<<<NDIM, 512, 0, stream>>>(x,  mt, ct, Qm, out + 1 + sz);
    fpack_kernel<<<(NDIM * DDIM + 255) / 256, 256, 0, stream>>>(f, Fm, NDIM * DDIM);

    loss_kernel<<<256, 512, 2 * SLOT, stream>>>(Fm, Km, Qm, part, out);
    reduce_kernel<<<392, 256, 0, stream>>>(part, out);
}